// Round 3
// baseline (249.157 us; speedup 1.0000x reference)
//
#include <hip/hip_runtime.h>
#include <math.h>

#define BG   256                   // graphs
#define NN   512                   // nodes per graph
#define EPG  (NN * 16)             // 8192 edges per graph
#define NE   (BG * EPG)            // 2097152 edges
#define N0   (BG * NN)             // 131072
#define K1   256
#define N1_  (BG * K1)             // 65536
#define K2   128
#define N2_  (BG * K2)             // 32768

__device__ __forceinline__ float4 f4fma(float s, float4 a, float4 c) {
    c.x = fmaf(s, a.x, c.x); c.y = fmaf(s, a.y, c.y);
    c.z = fmaf(s, a.z, c.z); c.w = fmaf(s, a.w, c.w);
    return c;
}

// ---- fused stage head (512 threads/block): unchanged from r11 ----
// blocks [0,BG): CSR build (pairs.x = LOCAL src); blocks [BG,..): 64x64 GEMM.
template <int NPG, bool REMAP>
__global__ __launch_bounds__(512)
void stage_head_kernel(const int* __restrict__ esrc, const int* __restrict__ edst,
                       const float* __restrict__ eatt, const int* __restrict__ nid,
                       int2* __restrict__ pairs, int* __restrict__ rowstart,
                       int* __restrict__ rowcnt, float* __restrict__ dinv,
                       const float4* __restrict__ X4, const float4* __restrict__ W4,
                       float4* __restrict__ Y4, int nrows, int mmb) {
    __shared__ __align__(16) char smem[52224];   // max(csr 41K, gemm 51K)
    if ((int)blockIdx.x < BG) {
        int2*  lpair = (int2*)smem;                      // [4096] staging, 32 KB
        int*   cnt   = (int*)(smem + 32768);             // [NPG]
        float* wsum  = (float*)(smem + 32768) + NPG;     // [NPG]
        int*   scn   = (int*)(smem + 32768) + 2 * NPG;   // [NPG]
        float* sdinv = (float*)(smem + 32768) + 3 * NPG; // [NPG]
        int*   wtot  = (int*)(smem + 32768) + 4 * NPG;   // [8]
        int g = blockIdx.x;
        int e0 = g * EPG, nbase = g * NPG;
        for (int ii = threadIdx.x; ii < NPG; ii += 512) { cnt[ii] = 0; wsum[ii] = 0.f; }
        __syncthreads();
        const int4*   edst4 = (const int4*)(edst + e0);
        const int4*   esrc4 = (const int4*)(esrc + e0);
        const float4* eatt4 = (const float4*)(eatt + e0);
        int ed[16]; int es[16]; float ea[16];
#pragma unroll
        for (int c = 0; c < 4; ++c) {            // single global read pass
            int ch = threadIdx.x + c * 512;
            int4   dd = edst4[ch];
            int4   ss = esrc4[ch];
            float4 ww = eatt4[ch];
            ed[c * 4 + 0] = dd.x; ed[c * 4 + 1] = dd.y; ed[c * 4 + 2] = dd.z; ed[c * 4 + 3] = dd.w;
            es[c * 4 + 0] = ss.x; es[c * 4 + 1] = ss.y; es[c * 4 + 2] = ss.z; es[c * 4 + 3] = ss.w;
            ea[c * 4 + 0] = ww.x; ea[c * 4 + 1] = ww.y; ea[c * 4 + 2] = ww.z; ea[c * 4 + 3] = ww.w;
        }
        if (REMAP) {
#pragma unroll
            for (int j = 0; j < 16; ++j) { ed[j] = nid[ed[j]]; es[j] = nid[es[j]]; }
        }
#pragma unroll
        for (int j = 0; j < 16; ++j) {
            bool valid = !REMAP || (ed[j] >= 0 && es[j] >= 0);
            if (valid) {
                int dl = ed[j] - nbase;
                atomicAdd(&cnt[dl], 1);
                atomicAdd(&wsum[dl], ea[j]);
            }
        }
        __syncthreads();
        int i = threadIdx.x;
        int lane = i & 63, wvid = i >> 6;
        int xval = (i < NPG) ? cnt[i] : 0;
        int xs = xval;
#pragma unroll
        for (int off = 1; off < 64; off <<= 1) {
            int v = __shfl_up(xs, off, 64);
            if (lane >= off) xs += v;
        }
        if (lane == 63) wtot[wvid] = xs;
        __syncthreads();
        int woff = 0, total = 0;
#pragma unroll
        for (int t = 0; t < 8; ++t) {
            int wt = wtot[t];
            if (t < wvid) woff += wt;
            total += wt;
        }
        xs += woff;                              // inclusive scan
        if (i < NPG) {
            int st = xs - xval;                  // exclusive
            rowstart[nbase + i] = e0 + st;
            rowcnt[nbase + i]   = xval;
            float di = rsqrtf(wsum[i] + 1.0f);
            dinv[nbase + i] = di;
            sdinv[i] = di;
            scn[i] = st;                          // running slot offset
        }
        __syncthreads();
        int slots[16]; float cf[16];
#pragma unroll
        for (int j = 0; j < 16; ++j) {
            bool valid = !REMAP || (ed[j] >= 0 && es[j] >= 0);
            slots[j] = -1;
            if (valid) {
                int dl = ed[j] - nbase, sl = es[j] - nbase;
                cf[j] = sdinv[dl] * ea[j] * sdinv[sl];
                slots[j] = atomicAdd(&scn[dl], 1);
            }
        }
#pragma unroll
        for (int j = 0; j < 16; ++j)
            if (slots[j] >= 0 && slots[j] < 4096)
                lpair[slots[j]] = make_int2(es[j] - nbase, __float_as_int(cf[j]));
        __syncthreads();
        int n0 = total < 4096 ? total : 4096;
        for (int k = threadIdx.x; k < n0; k += 512) pairs[e0 + k] = lpair[k];
        __syncthreads();
        if (total > 4096) {
#pragma unroll
            for (int j = 0; j < 16; ++j)
                if (slots[j] >= 4096)
                    lpair[slots[j] - 4096] = make_int2(es[j] - nbase, __float_as_int(cf[j]));
            __syncthreads();
            int n1 = total - 4096;
            for (int k = threadIdx.x; k < n1; k += 512) pairs[e0 + 4096 + k] = lpair[k];
        }
    } else {
        // ---------------- GEMM: Y[nrows,64] = X @ W ----------------
        float (*sW)[68] = (float (*)[68])smem;                       // 17408 B
        int p = threadIdx.x >> 8;                                    // pipeline 0/1
        int t = threadIdx.x & 255;
        float (*sX)[68] = (float (*)[68])(smem + 17408 + p * 17408);
#pragma unroll
        for (int u = 0; u < 2; ++u) {            // stage W once (all 512 threads)
            int idx = threadIdx.x + u * 512;
            int r = idx >> 4, c4 = idx & 15;
            *(float4*)&sW[r][c4 * 4] = W4[idx];
        }
        int mb = blockIdx.x - BG;
        int ntiles = nrows >> 6;
        int rg = t >> 4, cg = t & 15;
        for (int tile = mb * 2 + p; tile < ntiles; tile += mmb * 2) {
            __syncthreads();                     // protect sX reuse; covers sW stage
            int row0 = tile << 6;
#pragma unroll
            for (int u = 0; u < 4; ++u) {        // stage 64 rows of X
                int idx = t + u * 256;
                int r = idx >> 4, c4 = idx & 15;
                *(float4*)&sX[r][c4 * 4] = X4[(size_t)(row0 + r) * 16 + c4];
            }
            __syncthreads();
            float4 acc0 = make_float4(0.f, 0.f, 0.f, 0.f);
            float4 acc1 = acc0, acc2 = acc0, acc3 = acc0;
#pragma unroll
            for (int k4 = 0; k4 < 16; ++k4) {
                float4 xv0 = *(const float4*)&sX[rg * 4 + 0][k4 * 4];
                float4 xv1 = *(const float4*)&sX[rg * 4 + 1][k4 * 4];
                float4 xv2 = *(const float4*)&sX[rg * 4 + 2][k4 * 4];
                float4 xv3 = *(const float4*)&sX[rg * 4 + 3][k4 * 4];
                float4 wv0 = *(const float4*)&sW[k4 * 4 + 0][cg * 4];
                float4 wv1 = *(const float4*)&sW[k4 * 4 + 1][cg * 4];
                float4 wv2 = *(const float4*)&sW[k4 * 4 + 2][cg * 4];
                float4 wv3 = *(const float4*)&sW[k4 * 4 + 3][cg * 4];
                acc0 = f4fma(xv0.x, wv0, acc0); acc0 = f4fma(xv0.y, wv1, acc0);
                acc0 = f4fma(xv0.z, wv2, acc0); acc0 = f4fma(xv0.w, wv3, acc0);
                acc1 = f4fma(xv1.x, wv0, acc1); acc1 = f4fma(xv1.y, wv1, acc1);
                acc1 = f4fma(xv1.z, wv2, acc1); acc1 = f4fma(xv1.w, wv3, acc1);
                acc2 = f4fma(xv2.x, wv0, acc2); acc2 = f4fma(xv2.y, wv1, acc2);
                acc2 = f4fma(xv2.z, wv2, acc2); acc2 = f4fma(xv2.w, wv3, acc2);
                acc3 = f4fma(xv3.x, wv0, acc3); acc3 = f4fma(xv3.y, wv1, acc3);
                acc3 = f4fma(xv3.z, wv2, acc3); acc3 = f4fma(xv3.w, wv3, acc3);
            }
            size_t ob = (size_t)(row0 + rg * 4) * 16 + cg;
            Y4[ob]      = acc0;
            Y4[ob + 16] = acc1;
            Y4[ob + 32] = acc2;
            Y4[ob + 48] = acc3;
        }
    }
}

// ---- per-graph megafused tail, r14: group-cooperative conv.
// 16-lane group owns 4 nodes; per j-iteration the wave issues 4 independent
// ds_read_b128 (each = 4 whole rows, 16B/lane: stride 68 = 17 float4s odd ->
// the 16 chunks of a row span all 8 bank-groups exactly twice, deterministic
// uniform for ANY neighbor index) feeding 4 independent FMA chains (ILP=4,
// loop overhead amortized over 16 edges/iter — fixes r13's serialization).
// Exhausted nodes pad with cf=0 (fma(0,x,a)=a); per-node j-order preserved.
// All other phases r12-verbatim.
template <int NPG, int K, bool FINAL>
__global__ __launch_bounds__(1024)
void tail_kernel(const float4* __restrict__ hx4, const int2* __restrict__ pairs,
                 const int* __restrict__ rowstart, const int* __restrict__ rowcnt,
                 const float* __restrict__ dinv, const float4* __restrict__ b4,
                 const float4* __restrict__ wp4, const float* __restrict__ bp,
                 int* __restrict__ nid, float4* __restrict__ xn4,
                 float* __restrict__ xr, const float* __restrict__ x1r,
                 float* __restrict__ out) {
    constexpr int PASSES = NPG / 32;         // for t<512 verbatim phases
    constexpr int CP = (NPG + 255) / 256;    // conv passes: 2 (512) or 1 (256)
    constexpr int RLOG = (NPG == 512) ? 9 : 8;
    constexpr int RCH = NPG * NPG / 1024;    // rank chunk (256 or 64)
    constexpr int SH_A  = NPG * 68;          // shx: hx -> h
    constexpr int SH_UN = 4096;              // union: {perm,shp} then {smx,ssm}
    __shared__ __align__(16) float smem[SH_A + SH_UN + 2 * NPG + 64 + 64];
    float*  shx  = smem;
    int*    perm = (int*)(smem + SH_A);                  // [NPG]   (conv/score)
    float*  shp  = smem + SH_A + NPG;                    // [NPG]   (score)
    float4* smx  = (float4*)(smem + SH_A);               // [32*16] (final, overlays)
    float4* ssm  = (float4*)(smem + SH_A + 2048);        // [32*16]
    float*  ssc  = smem + SH_A + SH_UN;                  // [NPG]
    int*    rnk  = (int*)(smem + SH_A + SH_UN + NPG);    // [NPG]
    float*  sbw  = smem + SH_A + SH_UN + 2 * NPG;        // [64] bias
    int*    hist = (int*)(smem + SH_A + SH_UN + 2 * NPG + 64); // [64]

    int g = blockIdx.x, nbase = g * NPG;
    int t = threadIdx.x;
    int lane16 = t & 15, lane = t & 63;

    // phase 1: stage hx; bias; zero rank; degree histogram
    for (int i = t; i < NPG * 16; i += 1024) {
        int r = i >> 4, c4 = i & 15;
        *(float4*)&shx[r * 68 + c4 * 4] = hx4[(size_t)nbase * 16 + i];
    }
    if (t < 64) { sbw[t] = ((const float*)b4)[t]; hist[t] = 0; }
    for (int i = t; i < NPG; i += 1024) rnk[i] = 0;
    __syncthreads();
    for (int i = t; i < NPG; i += 1024) {
        int c = min(rowcnt[nbase + i], 63);
        atomicAdd(&hist[c], 1);
    }
    __syncthreads();
    if (t < 64) {                             // exclusive scan of 64 bins (1 wave)
        int v = hist[t], s = v;
#pragma unroll
        for (int off = 1; off < 64; off <<= 1) {
            int u = __shfl_up(s, off, 64);
            if (lane >= off) s += u;
        }
        hist[t] = s - v;
    }
    __syncthreads();
    for (int i = t; i < NPG; i += 1024) {
        int c = min(rowcnt[nbase + i], 63);
        int pos = atomicAdd(&hist[c], 1);
        perm[pos] = i;                        // sorted by degree -> lanes
    }
    __syncthreads();
    // phase 2: group-cooperative conv (16-lane group x 4 nodes)
    {
        int grp = t >> 4;                     // 0..63
        float4 acc[CP][4];
        int    nls[CP][4];
#pragma unroll
        for (int p = 0; p < CP; ++p) {
            int slot0 = p * 256 + grp * 4;
            int stk[4], cnk[4];
            int2 pf0[4], pf1[4];
            int mc = 0;
#pragma unroll
            for (int k = 0; k < 4; ++k) {
                int nl = perm[slot0 + k];
                nls[p][k] = nl;
                stk[k] = rowstart[nbase + nl];
                cnk[k] = rowcnt[nbase + nl];
                mc = max(mc, cnk[k]);
                float di = dinv[nbase + nl], dii = di * di;
                float4 xv = *(const float4*)&shx[nl * 68 + lane16 * 4];
                float4 a;
                a.x = fmaf(xv.x, dii, sbw[lane16 * 4 + 0]);
                a.y = fmaf(xv.y, dii, sbw[lane16 * 4 + 1]);
                a.z = fmaf(xv.z, dii, sbw[lane16 * 4 + 2]);
                a.w = fmaf(xv.w, dii, sbw[lane16 * 4 + 3]);
                acc[p][k] = a;
                pf0[k] = (cnk[k] > 0) ? pairs[stk[k]]     : make_int2(0, 0);
                pf1[k] = (cnk[k] > 1) ? pairs[stk[k] + 1] : make_int2(0, 0);
            }
            for (int j = 0; j < mc; ++j) {
#pragma unroll
                for (int k = 0; k < 4; ++k) {
                    int2 pf2 = (j + 2 < cnk[k]) ? pairs[stk[k] + j + 2]
                                                : make_int2(0, 0);
                    float cf = __int_as_float(pf0[k].y);
                    acc[p][k] = f4fma(cf,
                        *(const float4*)&shx[pf0[k].x * 68 + lane16 * 4],
                        acc[p][k]);
                    pf0[k] = pf1[k]; pf1[k] = pf2;
                }
            }
#pragma unroll
            for (int k = 0; k < 4; ++k) {
                float4 a = acc[p][k];
                a.x = fmaxf(a.x, 0.f); a.y = fmaxf(a.y, 0.f);
                a.z = fmaxf(a.z, 0.f); a.w = fmaxf(a.w, 0.f);
                acc[p][k] = a;
            }
        }
        __syncthreads();                      // all conv reads of hx complete
#pragma unroll
        for (int p = 0; p < CP; ++p)
#pragma unroll
            for (int k = 0; k < 4; ++k)
                *(float4*)&shx[nls[p][k] * 68 + lane16 * 4] = acc[p][k];
    }
    __syncthreads();
    // hp = h . Wp  (r11-verbatim on t<512 -> bitwise identical)
    if (t < 512) {
        int wv8 = t >> 6, sub4 = (t >> 4) & 3;
        float4 w4 = wp4[lane16];
#pragma unroll
        for (int p = 0; p < PASSES; ++p) {
            int n2 = p * 32 + wv8 * 4 + sub4;
            float4 a = *(const float4*)&shx[n2 * 68 + lane16 * 4];
            float tt = a.x * w4.x + a.y * w4.y + a.z * w4.z + a.w * w4.w;
            tt += __shfl_xor(tt, 1, 64); tt += __shfl_xor(tt, 2, 64);
            tt += __shfl_xor(tt, 4, 64); tt += __shfl_xor(tt, 8, 64);
            if (lane16 == 0) shp[n2] = tt;
        }
    }
    __syncthreads();
    // score conv (r11-verbatim math; perm mapping; pairs prefetch depth 2)
    if (t < NPG) {
        int i = perm[t];
        int st = rowstart[nbase + i], cn = rowcnt[nbase + i];
        float di = dinv[nbase + i];
        float a = fmaf(shp[i], di * di, bp[0]);
        int2 q0 = (cn > 0) ? pairs[st] : make_int2(0, 0);
        int2 q1 = (cn > 1) ? pairs[st + 1] : make_int2(0, 0);
        for (int j = 0; j < cn; ++j) {
            int2 q2 = (j + 2 < cn) ? pairs[st + j + 2] : make_int2(0, 0);
            a = fmaf(__int_as_float(q0.y), shp[q0.x], a);
            q0 = q1; q1 = q2;
        }
        ssc[i] = a;
    }
    __syncthreads();
    // exact top-k rank, split into 1024/NPG integer partials per node
    {
        int part = t >> RLOG;
        int i = t & (NPG - 1);
        float si = ssc[i];
        int j0 = part * RCH;
        int rank = 0;
        for (int j = j0; j < j0 + RCH; j += 4) {     // ssc 16B-aligned, RCH%4==0
            float4 sj = *(const float4*)&ssc[j];
            rank += (sj.x > si) || (sj.x == si && j     < i);
            rank += (sj.y > si) || (sj.y == si && j + 1 < i);
            rank += (sj.z > si) || (sj.z == si && j + 2 < i);
            rank += (sj.w > si) || (sj.w == si && j + 3 < i);
        }
        atomicAdd(&rnk[i], rank);
    }
    __syncthreads();
    if (!FINAL)
        for (int i = t; i < NPG; i += 1024)
            nid[nbase + i] = (rnk[i] < K) ? (g * K + rnk[i]) : -1;
    // gated xn write + readout partials (r11-verbatim on t<512)
    float4 mx = make_float4(-3.402823466e38f, -3.402823466e38f, -3.402823466e38f, -3.402823466e38f);
    float4 sm = make_float4(0.f, 0.f, 0.f, 0.f);
    if (t < 512) {
        int wv8 = t >> 6, sub4 = (t >> 4) & 3;
#pragma unroll
        for (int p = 0; p < PASSES; ++p) {
            int n2 = p * 32 + wv8 * 4 + sub4;
            int r = rnk[n2];
            if (r < K) {
                float gt = tanhf(ssc[n2]);
                float4 v = *(const float4*)&shx[n2 * 68 + lane16 * 4];
                v.x *= gt; v.y *= gt; v.z *= gt; v.w *= gt;
                if (!FINAL) xn4[((size_t)g * K + r) * 16 + lane16] = v;
                mx.x = fmaxf(mx.x, v.x); mx.y = fmaxf(mx.y, v.y);
                mx.z = fmaxf(mx.z, v.z); mx.w = fmaxf(mx.w, v.w);
                sm.x += v.x; sm.y += v.y; sm.z += v.z; sm.w += v.w;
            }
        }
    }
    int grp = t >> 4;                        // 0..31 for t<512
    __syncthreads();                         // perm/shp dead; smx/ssm overlay safe
    if (t < 512) {
        smx[grp * 16 + lane16] = mx;
        ssm[grp * 16 + lane16] = sm;
    }
    __syncthreads();
    if (grp == 0) {
#pragma unroll
        for (int u = 1; u < 32; ++u) {
            float4 a = smx[u * 16 + lane16], b = ssm[u * 16 + lane16];
            mx.x = fmaxf(mx.x, a.x); mx.y = fmaxf(mx.y, a.y);
            mx.z = fmaxf(mx.z, a.z); mx.w = fmaxf(mx.w, a.w);
            sm.x += b.x; sm.y += b.y; sm.z += b.z; sm.w += b.w;
        }
        float invK = 1.f / K;
        int c = lane16 * 4;
        float mr[4] = {mx.x, mx.y, mx.z, mx.w};
        float ar[4] = {sm.x * invK, sm.y * invK, sm.z * invK, sm.w * invK};
#pragma unroll
        for (int u = 0; u < 4; ++u) {
            if (FINAL) {
                out[g * 128 + c + u]      = 0.5f * (x1r[g * 128 + c + u]      + mr[u]);
                out[g * 128 + 64 + c + u] = 0.5f * (x1r[g * 128 + 64 + c + u] + ar[u]);
            } else {
                xr[g * 128 + c + u]      = mr[u];
                xr[g * 128 + 64 + c + u] = ar[u];
            }
        }
    }
}

extern "C" void kernel_launch(void* const* d_in, const int* in_sizes, int n_in,
                              void* d_out, int out_size, void* d_ws, size_t ws_size,
                              hipStream_t stream) {
    const float* x    = (const float*)d_in[0];
    const float* eatt = (const float*)d_in[1];
    const float* W1   = (const float*)d_in[2];
    const float* b1   = (const float*)d_in[3];
    const float* Wp1  = (const float*)d_in[4];
    const float* bp1  = (const float*)d_in[5];
    const float* W2   = (const float*)d_in[6];
    const float* b2   = (const float*)d_in[7];
    const float* Wp2  = (const float*)d_in[8];
    const float* bp2  = (const float*)d_in[9];
    const int*   esrc = (const int*)d_in[10];
    const int*   edst = (const int*)d_in[11];
    float* out = (float*)d_out;

    float* ws = (float*)d_ws;
    size_t o = 0;
    float* A    = ws + o; o += (size_t)N0 * 64;   // hx1 -> hx2
    float* xn1  = ws + o; o += (size_t)N1_ * 64;
    int2*  prs  = (int2*)(ws + o); o += (size_t)NE * 2;  // (local src,coef) per slot
    int*   rst  = (int*)(ws + o); o += N0;
    int*   rcn  = (int*)(ws + o); o += N0;
    float* dinv = ws + o; o += N0;
    int*   nid  = (int*)(ws + o); o += N0;
    float* x1r  = ws + o; o += BG * 128;

    float* hx1 = A;
    float* hx2 = A;                        // hx1 dead after tail1

    // ---- stage 1 ----
    stage_head_kernel<NN, false><<<BG + 512, 512, 0, stream>>>(
        esrc, edst, eatt, nullptr, prs, rst, rcn, dinv,
        (const float4*)x, (const float4*)W1, (float4*)hx1, N0, 512);
    tail_kernel<NN, K1, false><<<BG, 1024, 0, stream>>>(
        (const float4*)hx1, prs, rst, rcn, dinv, (const float4*)b1,
        (const float4*)Wp1, bp1, nid, (float4*)xn1, x1r, nullptr, nullptr);
    // ---- stage 2 ----
    stage_head_kernel<K1, true><<<BG + 256, 512, 0, stream>>>(
        esrc, edst, eatt, nid, prs, rst, rcn, dinv,
        (const float4*)xn1, (const float4*)W2, (float4*)hx2, N1_, 256);
    tail_kernel<K1, K2, true><<<BG, 1024, 0, stream>>>(
        (const float4*)hx2, prs, rst, rcn, dinv, (const float4*)b2,
        (const float4*)Wp2, bp2, nullptr, nullptr, nullptr, x1r, out);
}

// Round 4
// 222.919 us; speedup vs baseline: 1.1177x; 1.1177x over previous
//
#include <hip/hip_runtime.h>
#include <math.h>

#define BG   256                   // graphs
#define NN   512                   // nodes per graph
#define EPG  (NN * 16)             // 8192 edges per graph
#define NE   (BG * EPG)            // 2097152 edges
#define N0   (BG * NN)             // 131072
#define K1   256
#define N1_  (BG * K1)             // 65536
#define K2   128
#define N2_  (BG * K2)             // 32768

__device__ __forceinline__ float4 f4fma(float s, float4 a, float4 c) {
    c.x = fmaf(s, a.x, c.x); c.y = fmaf(s, a.y, c.y);
    c.z = fmaf(s, a.z, c.z); c.w = fmaf(s, a.w, c.w);
    return c;
}

// ---- fused stage head (512 threads/block): unchanged from r11 ----
// blocks [0,BG): CSR build (pairs.x = LOCAL src); blocks [BG,..): 64x64 GEMM.
template <int NPG, bool REMAP>
__global__ __launch_bounds__(512)
void stage_head_kernel(const int* __restrict__ esrc, const int* __restrict__ edst,
                       const float* __restrict__ eatt, const int* __restrict__ nid,
                       int2* __restrict__ pairs, int* __restrict__ rowstart,
                       int* __restrict__ rowcnt, float* __restrict__ dinv,
                       const float4* __restrict__ X4, const float4* __restrict__ W4,
                       float4* __restrict__ Y4, int nrows, int mmb) {
    __shared__ __align__(16) char smem[52224];   // max(csr 41K, gemm 51K)
    if ((int)blockIdx.x < BG) {
        int2*  lpair = (int2*)smem;                      // [4096] staging, 32 KB
        int*   cnt   = (int*)(smem + 32768);             // [NPG]
        float* wsum  = (float*)(smem + 32768) + NPG;     // [NPG]
        int*   scn   = (int*)(smem + 32768) + 2 * NPG;   // [NPG]
        float* sdinv = (float*)(smem + 32768) + 3 * NPG; // [NPG]
        int*   wtot  = (int*)(smem + 32768) + 4 * NPG;   // [8]
        int g = blockIdx.x;
        int e0 = g * EPG, nbase = g * NPG;
        for (int ii = threadIdx.x; ii < NPG; ii += 512) { cnt[ii] = 0; wsum[ii] = 0.f; }
        __syncthreads();
        const int4*   edst4 = (const int4*)(edst + e0);
        const int4*   esrc4 = (const int4*)(esrc + e0);
        const float4* eatt4 = (const float4*)(eatt + e0);
        int ed[16]; int es[16]; float ea[16];
#pragma unroll
        for (int c = 0; c < 4; ++c) {            // single global read pass
            int ch = threadIdx.x + c * 512;
            int4   dd = edst4[ch];
            int4   ss = esrc4[ch];
            float4 ww = eatt4[ch];
            ed[c * 4 + 0] = dd.x; ed[c * 4 + 1] = dd.y; ed[c * 4 + 2] = dd.z; ed[c * 4 + 3] = dd.w;
            es[c * 4 + 0] = ss.x; es[c * 4 + 1] = ss.y; es[c * 4 + 2] = ss.z; es[c * 4 + 3] = ss.w;
            ea[c * 4 + 0] = ww.x; ea[c * 4 + 1] = ww.y; ea[c * 4 + 2] = ww.z; ea[c * 4 + 3] = ww.w;
        }
        if (REMAP) {
#pragma unroll
            for (int j = 0; j < 16; ++j) { ed[j] = nid[ed[j]]; es[j] = nid[es[j]]; }
        }
#pragma unroll
        for (int j = 0; j < 16; ++j) {
            bool valid = !REMAP || (ed[j] >= 0 && es[j] >= 0);
            if (valid) {
                int dl = ed[j] - nbase;
                atomicAdd(&cnt[dl], 1);
                atomicAdd(&wsum[dl], ea[j]);
            }
        }
        __syncthreads();
        int i = threadIdx.x;
        int lane = i & 63, wvid = i >> 6;
        int xval = (i < NPG) ? cnt[i] : 0;
        int xs = xval;
#pragma unroll
        for (int off = 1; off < 64; off <<= 1) {
            int v = __shfl_up(xs, off, 64);
            if (lane >= off) xs += v;
        }
        if (lane == 63) wtot[wvid] = xs;
        __syncthreads();
        int woff = 0, total = 0;
#pragma unroll
        for (int t = 0; t < 8; ++t) {
            int wt = wtot[t];
            if (t < wvid) woff += wt;
            total += wt;
        }
        xs += woff;                              // inclusive scan
        if (i < NPG) {
            int st = xs - xval;                  // exclusive
            rowstart[nbase + i] = e0 + st;
            rowcnt[nbase + i]   = xval;
            float di = rsqrtf(wsum[i] + 1.0f);
            dinv[nbase + i] = di;
            sdinv[i] = di;
            scn[i] = st;                          // running slot offset
        }
        __syncthreads();
        int slots[16]; float cf[16];
#pragma unroll
        for (int j = 0; j < 16; ++j) {
            bool valid = !REMAP || (ed[j] >= 0 && es[j] >= 0);
            slots[j] = -1;
            if (valid) {
                int dl = ed[j] - nbase, sl = es[j] - nbase;
                cf[j] = sdinv[dl] * ea[j] * sdinv[sl];
                slots[j] = atomicAdd(&scn[dl], 1);
            }
        }
#pragma unroll
        for (int j = 0; j < 16; ++j)
            if (slots[j] >= 0 && slots[j] < 4096)
                lpair[slots[j]] = make_int2(es[j] - nbase, __float_as_int(cf[j]));
        __syncthreads();
        int n0 = total < 4096 ? total : 4096;
        for (int k = threadIdx.x; k < n0; k += 512) pairs[e0 + k] = lpair[k];
        __syncthreads();
        if (total > 4096) {
#pragma unroll
            for (int j = 0; j < 16; ++j)
                if (slots[j] >= 4096)
                    lpair[slots[j] - 4096] = make_int2(es[j] - nbase, __float_as_int(cf[j]));
            __syncthreads();
            int n1 = total - 4096;
            for (int k = threadIdx.x; k < n1; k += 512) pairs[e0 + 4096 + k] = lpair[k];
        }
    } else {
        // ---------------- GEMM: Y[nrows,64] = X @ W ----------------
        float (*sW)[68] = (float (*)[68])smem;                       // 17408 B
        int p = threadIdx.x >> 8;                                    // pipeline 0/1
        int t = threadIdx.x & 255;
        float (*sX)[68] = (float (*)[68])(smem + 17408 + p * 17408);
#pragma unroll
        for (int u = 0; u < 2; ++u) {            // stage W once (all 512 threads)
            int idx = threadIdx.x + u * 512;
            int r = idx >> 4, c4 = idx & 15;
            *(float4*)&sW[r][c4 * 4] = W4[idx];
        }
        int mb = blockIdx.x - BG;
        int ntiles = nrows >> 6;
        int rg = t >> 4, cg = t & 15;
        for (int tile = mb * 2 + p; tile < ntiles; tile += mmb * 2) {
            __syncthreads();                     // protect sX reuse; covers sW stage
            int row0 = tile << 6;
#pragma unroll
            for (int u = 0; u < 4; ++u) {        // stage 64 rows of X
                int idx = t + u * 256;
                int r = idx >> 4, c4 = idx & 15;
                *(float4*)&sX[r][c4 * 4] = X4[(size_t)(row0 + r) * 16 + c4];
            }
            __syncthreads();
            float4 acc0 = make_float4(0.f, 0.f, 0.f, 0.f);
            float4 acc1 = acc0, acc2 = acc0, acc3 = acc0;
#pragma unroll
            for (int k4 = 0; k4 < 16; ++k4) {
                float4 xv0 = *(const float4*)&sX[rg * 4 + 0][k4 * 4];
                float4 xv1 = *(const float4*)&sX[rg * 4 + 1][k4 * 4];
                float4 xv2 = *(const float4*)&sX[rg * 4 + 2][k4 * 4];
                float4 xv3 = *(const float4*)&sX[rg * 4 + 3][k4 * 4];
                float4 wv0 = *(const float4*)&sW[k4 * 4 + 0][cg * 4];
                float4 wv1 = *(const float4*)&sW[k4 * 4 + 1][cg * 4];
                float4 wv2 = *(const float4*)&sW[k4 * 4 + 2][cg * 4];
                float4 wv3 = *(const float4*)&sW[k4 * 4 + 3][cg * 4];
                acc0 = f4fma(xv0.x, wv0, acc0); acc0 = f4fma(xv0.y, wv1, acc0);
                acc0 = f4fma(xv0.z, wv2, acc0); acc0 = f4fma(xv0.w, wv3, acc0);
                acc1 = f4fma(xv1.x, wv0, acc1); acc1 = f4fma(xv1.y, wv1, acc1);
                acc1 = f4fma(xv1.z, wv2, acc1); acc1 = f4fma(xv1.w, wv3, acc1);
                acc2 = f4fma(xv2.x, wv0, acc2); acc2 = f4fma(xv2.y, wv1, acc2);
                acc2 = f4fma(xv2.z, wv2, acc2); acc2 = f4fma(xv2.w, wv3, acc2);
                acc3 = f4fma(xv3.x, wv0, acc3); acc3 = f4fma(xv3.y, wv1, acc3);
                acc3 = f4fma(xv3.z, wv2, acc3); acc3 = f4fma(xv3.w, wv3, acc3);
            }
            size_t ob = (size_t)(row0 + rg * 4) * 16 + cg;
            Y4[ob]      = acc0;
            Y4[ob + 16] = acc1;
            Y4[ob + 32] = acc2;
            Y4[ob + 48] = acc3;
        }
    }
}

// ---- per-graph megafused tail, r15: r12 structure + 8-deep chunked
// register prefetch on the pairs stream (conv + score conv). r12's depth-2
// prefetch covered ~190 cyc vs ~500-900 cyc L2/HBM latency -> per-iteration
// stall was the dominant cost (VALUBusy 30%). Chunk-8 double-buffer puts
// issue-to-use distance at ~1 chunk of work (~700+ cyc). Padded entries use
// cf=0: fmaf(0,finite,acc)=acc exactly; per-node j-order preserved.
// Both tails use the proven LPN=2 conv shape (tail2: lanes t<512 active).
template <int NPG, int K, bool FINAL>
__global__ __launch_bounds__(1024)
void tail_kernel(const float4* __restrict__ hx4, const int2* __restrict__ pairs,
                 const int* __restrict__ rowstart, const int* __restrict__ rowcnt,
                 const float* __restrict__ dinv, const float4* __restrict__ b4,
                 const float4* __restrict__ wp4, const float* __restrict__ bp,
                 int* __restrict__ nid, float4* __restrict__ xn4,
                 float* __restrict__ xr, const float* __restrict__ x1r,
                 float* __restrict__ out) {
    constexpr int PASSES = NPG / 32;         // for t<512 verbatim phases
    constexpr int RLOG = (NPG == 512) ? 9 : 8;
    constexpr int RCH = NPG * NPG / 1024;    // rank chunk (256 or 64)
    constexpr int SH_A  = NPG * 68;          // shx: hx -> h
    constexpr int SH_UN = 4096;              // union: {perm,shp} then {smx,ssm}
    __shared__ __align__(16) float smem[SH_A + SH_UN + 2 * NPG + 64 + 64];
    float*  shx  = smem;
    int*    perm = (int*)(smem + SH_A);                  // [NPG]   (conv/score)
    float*  shp  = smem + SH_A + NPG;                    // [NPG]   (score)
    float4* smx  = (float4*)(smem + SH_A);               // [32*16] (final, overlays)
    float4* ssm  = (float4*)(smem + SH_A + 2048);        // [32*16]
    float*  ssc  = smem + SH_A + SH_UN;                  // [NPG]
    int*    rnk  = (int*)(smem + SH_A + SH_UN + NPG);    // [NPG]
    float*  sbw  = smem + SH_A + SH_UN + 2 * NPG;        // [64] bias
    int*    hist = (int*)(smem + SH_A + SH_UN + 2 * NPG + 64); // [64]

    int g = blockIdx.x, nbase = g * NPG;
    int t = threadIdx.x;
    int lane16 = t & 15, lane = t & 63;

    // phase 1: stage hx; bias; zero rank; degree histogram
    for (int i = t; i < NPG * 16; i += 1024) {
        int r = i >> 4, c4 = i & 15;
        *(float4*)&shx[r * 68 + c4 * 4] = hx4[(size_t)nbase * 16 + i];
    }
    if (t < 64) { sbw[t] = ((const float*)b4)[t]; hist[t] = 0; }
    for (int i = t; i < NPG; i += 1024) rnk[i] = 0;
    __syncthreads();
    for (int i = t; i < NPG; i += 1024) {
        int c = min(rowcnt[nbase + i], 63);
        atomicAdd(&hist[c], 1);
    }
    __syncthreads();
    if (t < 64) {                             // exclusive scan of 64 bins (1 wave)
        int v = hist[t], s = v;
#pragma unroll
        for (int off = 1; off < 64; off <<= 1) {
            int u = __shfl_up(s, off, 64);
            if (lane >= off) s += u;
        }
        hist[t] = s - v;
    }
    __syncthreads();
    for (int i = t; i < NPG; i += 1024) {
        int c = min(rowcnt[nbase + i], 63);
        int pos = atomicAdd(&hist[c], 1);
        perm[pos] = i;                        // sorted by degree -> lanes
    }
    __syncthreads();
    // phase 2: conv — 2 lanes per node (half-row each, proven r12 shape),
    // 8-deep chunked register prefetch on pairs.
    {
        int idx2 = t >> 1;                    // node slot
        int half = t & 1;
        int fb = half * 8;                    // float4 column base
        float4 acc[8];
        int nl = 0;
        if (idx2 < NPG) {
            nl = perm[idx2];
            int st = rowstart[nbase + nl], cn = rowcnt[nbase + nl];
            float di = dinv[nbase + nl], dii = di * di;
#pragma unroll
            for (int c = 0; c < 8; ++c) {
                float4 xv = *(const float4*)&shx[nl * 68 + (fb + c) * 4];
                acc[c].x = fmaf(xv.x, dii, sbw[(fb + c) * 4 + 0]);
                acc[c].y = fmaf(xv.y, dii, sbw[(fb + c) * 4 + 1]);
                acc[c].z = fmaf(xv.z, dii, sbw[(fb + c) * 4 + 2]);
                acc[c].w = fmaf(xv.w, dii, sbw[(fb + c) * 4 + 3]);
            }
            int2 buf[8];
#pragma unroll
            for (int u = 0; u < 8; ++u)
                buf[u] = (u < cn) ? pairs[st + u] : make_int2(0, 0);
            for (int base = 0; base < cn; base += 8) {
                int2 nbuf[8];
#pragma unroll
                for (int u = 0; u < 8; ++u) {
                    int jj = base + 8 + u;
                    nbuf[u] = (jj < cn) ? pairs[st + jj] : make_int2(0, 0);
                }
#pragma unroll
                for (int u = 0; u < 8; ++u) {
                    float cf = __int_as_float(buf[u].y);
                    int   s  = buf[u].x;
#pragma unroll
                    for (int c = 0; c < 8; ++c)
                        acc[c] = f4fma(cf, *(const float4*)&shx[s * 68 + (fb + c) * 4], acc[c]);
                }
#pragma unroll
                for (int u = 0; u < 8; ++u) buf[u] = nbuf[u];
            }
#pragma unroll
            for (int c = 0; c < 8; ++c) {
                acc[c].x = fmaxf(acc[c].x, 0.f); acc[c].y = fmaxf(acc[c].y, 0.f);
                acc[c].z = fmaxf(acc[c].z, 0.f); acc[c].w = fmaxf(acc[c].w, 0.f);
            }
        }
        __syncthreads();                      // all conv reads of hx complete
        if (idx2 < NPG) {
#pragma unroll
            for (int c = 0; c < 8; ++c)
                *(float4*)&shx[nl * 68 + (fb + c) * 4] = acc[c];  // h over hx
        }
    }
    __syncthreads();
    // hp = h . Wp  (r11-verbatim on t<512 -> bitwise identical)
    if (t < 512) {
        int wv8 = t >> 6, sub4 = (t >> 4) & 3;
        float4 w4 = wp4[lane16];
#pragma unroll
        for (int p = 0; p < PASSES; ++p) {
            int n2 = p * 32 + wv8 * 4 + sub4;
            float4 a = *(const float4*)&shx[n2 * 68 + lane16 * 4];
            float tt = a.x * w4.x + a.y * w4.y + a.z * w4.z + a.w * w4.w;
            tt += __shfl_xor(tt, 1, 64); tt += __shfl_xor(tt, 2, 64);
            tt += __shfl_xor(tt, 4, 64); tt += __shfl_xor(tt, 8, 64);
            if (lane16 == 0) shp[n2] = tt;
        }
    }
    __syncthreads();
    // score conv (same math/order; 8-deep chunked prefetch on pairs)
    if (t < NPG) {
        int i = perm[t];
        int st = rowstart[nbase + i], cn = rowcnt[nbase + i];
        float di = dinv[nbase + i];
        float a = fmaf(shp[i], di * di, bp[0]);
        int2 buf[8];
#pragma unroll
        for (int u = 0; u < 8; ++u)
            buf[u] = (u < cn) ? pairs[st + u] : make_int2(0, 0);
        for (int base = 0; base < cn; base += 8) {
            int2 nbuf[8];
#pragma unroll
            for (int u = 0; u < 8; ++u) {
                int jj = base + 8 + u;
                nbuf[u] = (jj < cn) ? pairs[st + jj] : make_int2(0, 0);
            }
#pragma unroll
            for (int u = 0; u < 8; ++u)
                a = fmaf(__int_as_float(buf[u].y), shp[buf[u].x], a);
#pragma unroll
            for (int u = 0; u < 8; ++u) buf[u] = nbuf[u];
        }
        ssc[i] = a;
    }
    __syncthreads();
    // exact top-k rank, split into 1024/NPG integer partials per node
    {
        int part = t >> RLOG;
        int i = t & (NPG - 1);
        float si = ssc[i];
        int j0 = part * RCH;
        int rank = 0;
        for (int j = j0; j < j0 + RCH; j += 4) {     // ssc 16B-aligned, RCH%4==0
            float4 sj = *(const float4*)&ssc[j];
            rank += (sj.x > si) || (sj.x == si && j     < i);
            rank += (sj.y > si) || (sj.y == si && j + 1 < i);
            rank += (sj.z > si) || (sj.z == si && j + 2 < i);
            rank += (sj.w > si) || (sj.w == si && j + 3 < i);
        }
        atomicAdd(&rnk[i], rank);
    }
    __syncthreads();
    if (!FINAL)
        for (int i = t; i < NPG; i += 1024)
            nid[nbase + i] = (rnk[i] < K) ? (g * K + rnk[i]) : -1;
    // gated xn write + readout partials (r11-verbatim on t<512)
    float4 mx = make_float4(-3.402823466e38f, -3.402823466e38f, -3.402823466e38f, -3.402823466e38f);
    float4 sm = make_float4(0.f, 0.f, 0.f, 0.f);
    if (t < 512) {
        int wv8 = t >> 6, sub4 = (t >> 4) & 3;
#pragma unroll
        for (int p = 0; p < PASSES; ++p) {
            int n2 = p * 32 + wv8 * 4 + sub4;
            int r = rnk[n2];
            if (r < K) {
                float gt = tanhf(ssc[n2]);
                float4 v = *(const float4*)&shx[n2 * 68 + lane16 * 4];
                v.x *= gt; v.y *= gt; v.z *= gt; v.w *= gt;
                if (!FINAL) xn4[((size_t)g * K + r) * 16 + lane16] = v;
                mx.x = fmaxf(mx.x, v.x); mx.y = fmaxf(mx.y, v.y);
                mx.z = fmaxf(mx.z, v.z); mx.w = fmaxf(mx.w, v.w);
                sm.x += v.x; sm.y += v.y; sm.z += v.z; sm.w += v.w;
            }
        }
    }
    int grp = t >> 4;                        // 0..31 for t<512
    __syncthreads();                         // perm/shp dead; smx/ssm overlay safe
    if (t < 512) {
        smx[grp * 16 + lane16] = mx;
        ssm[grp * 16 + lane16] = sm;
    }
    __syncthreads();
    if (grp == 0) {
#pragma unroll
        for (int u = 1; u < 32; ++u) {
            float4 a = smx[u * 16 + lane16], b = ssm[u * 16 + lane16];
            mx.x = fmaxf(mx.x, a.x); mx.y = fmaxf(mx.y, a.y);
            mx.z = fmaxf(mx.z, a.z); mx.w = fmaxf(mx.w, a.w);
            sm.x += b.x; sm.y += b.y; sm.z += b.z; sm.w += b.w;
        }
        float invK = 1.f / K;
        int c = lane16 * 4;
        float mr[4] = {mx.x, mx.y, mx.z, mx.w};
        float ar[4] = {sm.x * invK, sm.y * invK, sm.z * invK, sm.w * invK};
#pragma unroll
        for (int u = 0; u < 4; ++u) {
            if (FINAL) {
                out[g * 128 + c + u]      = 0.5f * (x1r[g * 128 + c + u]      + mr[u]);
                out[g * 128 + 64 + c + u] = 0.5f * (x1r[g * 128 + 64 + c + u] + ar[u]);
            } else {
                xr[g * 128 + c + u]      = mr[u];
                xr[g * 128 + 64 + c + u] = ar[u];
            }
        }
    }
}

extern "C" void kernel_launch(void* const* d_in, const int* in_sizes, int n_in,
                              void* d_out, int out_size, void* d_ws, size_t ws_size,
                              hipStream_t stream) {
    const float* x    = (const float*)d_in[0];
    const float* eatt = (const float*)d_in[1];
    const float* W1   = (const float*)d_in[2];
    const float* b1   = (const float*)d_in[3];
    const float* Wp1  = (const float*)d_in[4];
    const float* bp1  = (const float*)d_in[5];
    const float* W2   = (const float*)d_in[6];
    const float* b2   = (const float*)d_in[7];
    const float* Wp2  = (const float*)d_in[8];
    const float* bp2  = (const float*)d_in[9];
    const int*   esrc = (const int*)d_in[10];
    const int*   edst = (const int*)d_in[11];
    float* out = (float*)d_out;

    float* ws = (float*)d_ws;
    size_t o = 0;
    float* A    = ws + o; o += (size_t)N0 * 64;   // hx1 -> hx2
    float* xn1  = ws + o; o += (size_t)N1_ * 64;
    int2*  prs  = (int2*)(ws + o); o += (size_t)NE * 2;  // (local src,coef) per slot
    int*   rst  = (int*)(ws + o); o += N0;
    int*   rcn  = (int*)(ws + o); o += N0;
    float* dinv = ws + o; o += N0;
    int*   nid  = (int*)(ws + o); o += N0;
    float* x1r  = ws + o; o += BG * 128;

    float* hx1 = A;
    float* hx2 = A;                        // hx1 dead after tail1

    // ---- stage 1 ----
    stage_head_kernel<NN, false><<<BG + 512, 512, 0, stream>>>(
        esrc, edst, eatt, nullptr, prs, rst, rcn, dinv,
        (const float4*)x, (const float4*)W1, (float4*)hx1, N0, 512);
    tail_kernel<NN, K1, false><<<BG, 1024, 0, stream>>>(
        (const float4*)hx1, prs, rst, rcn, dinv, (const float4*)b1,
        (const float4*)Wp1, bp1, nid, (float4*)xn1, x1r, nullptr, nullptr);
    // ---- stage 2 ----
    stage_head_kernel<K1, true><<<BG + 256, 512, 0, stream>>>(
        esrc, edst, eatt, nid, prs, rst, rcn, dinv,
        (const float4*)xn1, (const float4*)W2, (float4*)hx2, N1_, 256);
    tail_kernel<K1, K2, true><<<BG, 1024, 0, stream>>>(
        (const float4*)hx2, prs, rst, rcn, dinv, (const float4*)b2,
        (const float4*)Wp2, bp2, nullptr, nullptr, nullptr, x1r, out);
}

// Round 5
// 207.179 us; speedup vs baseline: 1.2026x; 1.0760x over previous
//
#include <hip/hip_runtime.h>
#include <math.h>

#define BG   256                   // graphs
#define NN   512                   // nodes per graph
#define EPG  (NN * 16)             // 8192 edges per graph
#define NE   (BG * EPG)            // 2097152 edges
#define N0   (BG * NN)             // 131072
#define K1   256
#define N1_  (BG * K1)             // 65536
#define K2   128
#define N2_  (BG * K2)             // 32768

__device__ __forceinline__ float4 f4fma(float s, float4 a, float4 c) {
    c.x = fmaf(s, a.x, c.x); c.y = fmaf(s, a.y, c.y);
    c.z = fmaf(s, a.z, c.z); c.w = fmaf(s, a.w, c.w);
    return c;
}

// ---- r16: per-graph MEGAKERNEL (one block = one graph, 1024 threads) ----
// Phases: A) CSR build (r11 logic re-shaped to 1024 thr; pairs->global, L2-hot)
//         B) stage x->shx[68-stride] + W->sW overlay
//         C) in-LDS 64x64-tile GEMM, head-verbatim FMA order -> hx bitwise id.
//         D) r12-verbatim conv/hp/score/rank/readout.
// Removes hx HBM round-trip (~60MB/iter) + 2 kernel launches per iter.
// LDS 160256B unchanged: CSR scratch (40KB) and sW (17KB) overlay dead regions.
template <int NPG, int K, bool REMAP, bool FINAL>
__global__ __launch_bounds__(1024)
void stage_kernel(const int* __restrict__ esrc, const int* __restrict__ edst,
                  const float* __restrict__ eatt, const int* __restrict__ nid_in,
                  int* __restrict__ nid_out,
                  int2* __restrict__ pairs, int* __restrict__ rowstart,
                  int* __restrict__ rowcnt, float* __restrict__ dinv,
                  const float4* __restrict__ X4, const float4* __restrict__ W4,
                  const float4* __restrict__ b4, const float4* __restrict__ wp4,
                  const float* __restrict__ bp,
                  float4* __restrict__ xn4, float* __restrict__ xr,
                  const float* __restrict__ x1r, float* __restrict__ out) {
    constexpr int PASSES = NPG / 32;
    constexpr int LPN = 1024 / NPG;          // 2 (stage1) or 4 (stage2)
    constexpr int LOG_LPN = (LPN == 2) ? 1 : 2;
    constexpr int QF = 16 / LPN;
    constexpr int RLOG = (NPG == 512) ? 9 : 8;
    constexpr int RCH = NPG * NPG / 1024;
    constexpr int SH_A  = NPG * 68;
    constexpr int SH_UN = 4096;
    __shared__ __align__(16) float smem[SH_A + SH_UN + 2 * NPG + 64 + 64];
    // tail overlays (r12-verbatim layout)
    float*  shx  = smem;
    int*    perm = (int*)(smem + SH_A);
    float*  shp  = smem + SH_A + NPG;
    float4* smx  = (float4*)(smem + SH_A);
    float4* ssm  = (float4*)(smem + SH_A + 2048);
    float*  ssc  = smem + SH_A + SH_UN;
    int*    rnk  = (int*)(smem + SH_A + SH_UN + NPG);
    float*  sbw  = smem + SH_A + SH_UN + 2 * NPG;
    int*    hist = (int*)(smem + SH_A + SH_UN + 2 * NPG + 64);
    // phase-A overlays (dead before phase B writes shx)
    int2*   lpair = (int2*)smem;                    // [4096] 32KB
    int*    cnt   = (int*)smem + 8192;              // [NPG]
    float*  wsum  = smem + 8192 + NPG;              // [NPG]
    int*    scn   = (int*)smem + 8192 + 2 * NPG;    // [NPG]
    float*  sdinv = smem + 8192 + 3 * NPG;          // [NPG]
    int*    wtot  = (int*)smem + 8192 + 4 * NPG;    // [16]
    // phase-B/C overlay: W tile (dead after phase C reads)
    float*  sWf   = smem + SH_A;                    // [64*68] 17KB

    int g = blockIdx.x, nbase = g * NPG, e0 = g * EPG;
    int t = threadIdx.x;
    int lane16 = t & 15, lane = t & 63;

    // ================= phase A: CSR build =================
    for (int i = t; i < NPG; i += 1024) { cnt[i] = 0; wsum[i] = 0.f; }
    __syncthreads();
    {
        const int4*   edst4 = (const int4*)(edst + e0);
        const int4*   esrc4 = (const int4*)(esrc + e0);
        const float4* eatt4 = (const float4*)(eatt + e0);
        int ed[8]; int es[8]; float ea[8];
#pragma unroll
        for (int c = 0; c < 2; ++c) {        // 8 edges/thread, single pass
            int ch = t + c * 1024;
            int4   dd = edst4[ch];
            int4   ss = esrc4[ch];
            float4 ww = eatt4[ch];
            ed[c * 4 + 0] = dd.x; ed[c * 4 + 1] = dd.y; ed[c * 4 + 2] = dd.z; ed[c * 4 + 3] = dd.w;
            es[c * 4 + 0] = ss.x; es[c * 4 + 1] = ss.y; es[c * 4 + 2] = ss.z; es[c * 4 + 3] = ss.w;
            ea[c * 4 + 0] = ww.x; ea[c * 4 + 1] = ww.y; ea[c * 4 + 2] = ww.z; ea[c * 4 + 3] = ww.w;
        }
        if (REMAP) {
#pragma unroll
            for (int j = 0; j < 8; ++j) { ed[j] = nid_in[ed[j]]; es[j] = nid_in[es[j]]; }
        }
#pragma unroll
        for (int j = 0; j < 8; ++j) {
            bool valid = !REMAP || (ed[j] >= 0 && es[j] >= 0);
            if (valid) {
                int dl = ed[j] - nbase;
                atomicAdd(&cnt[dl], 1);
                atomicAdd(&wsum[dl], ea[j]);
            }
        }
        __syncthreads();
        int wv = t >> 6;
        int xval = (t < NPG) ? cnt[t] : 0;
        int xs = xval;
#pragma unroll
        for (int off = 1; off < 64; off <<= 1) {
            int v = __shfl_up(xs, off, 64);
            if (lane >= off) xs += v;
        }
        if (lane == 63) wtot[wv] = xs;
        __syncthreads();
        int woff = 0, total = 0;
#pragma unroll
        for (int w = 0; w < 16; ++w) {
            int wt = wtot[w];
            if (w < wv) woff += wt;
            total += wt;
        }
        xs += woff;                          // inclusive scan
        if (t < NPG) {
            int st = xs - xval;              // exclusive
            rowstart[nbase + t] = e0 + st;
            rowcnt[nbase + t]   = xval;
            float di = rsqrtf(wsum[t] + 1.0f);
            dinv[nbase + t] = di;
            sdinv[t] = di;
            scn[t] = st;
        }
        __syncthreads();
        int slots[8]; float cf[8];
#pragma unroll
        for (int j = 0; j < 8; ++j) {
            bool valid = !REMAP || (ed[j] >= 0 && es[j] >= 0);
            slots[j] = -1;
            if (valid) {
                int dl = ed[j] - nbase, sl = es[j] - nbase;
                cf[j] = sdinv[dl] * ea[j] * sdinv[sl];
                slots[j] = atomicAdd(&scn[dl], 1);
            }
        }
#pragma unroll
        for (int j = 0; j < 8; ++j)
            if (slots[j] >= 0 && slots[j] < 4096)
                lpair[slots[j]] = make_int2(es[j] - nbase, __float_as_int(cf[j]));
        __syncthreads();
        int n0 = total < 4096 ? total : 4096;
        for (int k2 = t; k2 < n0; k2 += 1024) pairs[e0 + k2] = lpair[k2];
        __syncthreads();
        if (total > 4096) {
#pragma unroll
            for (int j = 0; j < 8; ++j)
                if (slots[j] >= 4096)
                    lpair[slots[j] - 4096] = make_int2(es[j] - nbase, __float_as_int(cf[j]));
            __syncthreads();
            int n1 = total - 4096;
            for (int k2 = t; k2 < n1; k2 += 1024) pairs[e0 + 4096 + k2] = lpair[k2];
            __syncthreads();
        }
    }
    __syncthreads();                         // CSR LDS dead

    // ================= phase B: stage x + W =================
    for (int i = t; i < NPG * 16; i += 1024) {
        int r = i >> 4, c4 = i & 15;
        *(float4*)&shx[r * 68 + c4 * 4] = X4[(size_t)nbase * 16 + i];
    }
    {   // 1024 threads == 64 rows x 16 float4 of W, exactly one step
        int r = t >> 4, c4 = t & 15;
        *(float4*)&sWf[r * 68 + c4 * 4] = W4[t];
    }
    __syncthreads();

    // ================= phase C: in-LDS GEMM hx = x @ W =================
    {
        constexpr int TILES = NPG / 64, TPG = TILES / 4;   // 2 or 1 tiles/group
        int q = t >> 8, tq = t & 255;
        int rg = tq >> 4, cg = tq & 15;
        float4 ac[TPG][4];
#pragma unroll
        for (int tt = 0; tt < TPG; ++tt) {
            int row0 = (tt * 4 + q) * 64;
            float4 acc0 = make_float4(0.f, 0.f, 0.f, 0.f);
            float4 acc1 = acc0, acc2 = acc0, acc3 = acc0;
#pragma unroll
            for (int k4 = 0; k4 < 16; ++k4) {      // head-verbatim FMA order
                float4 xv0 = *(const float4*)&shx[(row0 + rg * 4 + 0) * 68 + k4 * 4];
                float4 xv1 = *(const float4*)&shx[(row0 + rg * 4 + 1) * 68 + k4 * 4];
                float4 xv2 = *(const float4*)&shx[(row0 + rg * 4 + 2) * 68 + k4 * 4];
                float4 xv3 = *(const float4*)&shx[(row0 + rg * 4 + 3) * 68 + k4 * 4];
                float4 wv0 = *(const float4*)&sWf[(k4 * 4 + 0) * 68 + cg * 4];
                float4 wv1 = *(const float4*)&sWf[(k4 * 4 + 1) * 68 + cg * 4];
                float4 wv2 = *(const float4*)&sWf[(k4 * 4 + 2) * 68 + cg * 4];
                float4 wv3 = *(const float4*)&sWf[(k4 * 4 + 3) * 68 + cg * 4];
                acc0 = f4fma(xv0.x, wv0, acc0); acc0 = f4fma(xv0.y, wv1, acc0);
                acc0 = f4fma(xv0.z, wv2, acc0); acc0 = f4fma(xv0.w, wv3, acc0);
                acc1 = f4fma(xv1.x, wv0, acc1); acc1 = f4fma(xv1.y, wv1, acc1);
                acc1 = f4fma(xv1.z, wv2, acc1); acc1 = f4fma(xv1.w, wv3, acc1);
                acc2 = f4fma(xv2.x, wv0, acc2); acc2 = f4fma(xv2.y, wv1, acc2);
                acc2 = f4fma(xv2.z, wv2, acc2); acc2 = f4fma(xv2.w, wv3, acc2);
                acc3 = f4fma(xv3.x, wv0, acc3); acc3 = f4fma(xv3.y, wv1, acc3);
                acc3 = f4fma(xv3.z, wv2, acc3); acc3 = f4fma(xv3.w, wv3, acc3);
            }
            ac[tt][0] = acc0; ac[tt][1] = acc1; ac[tt][2] = acc2; ac[tt][3] = acc3;
        }
        __syncthreads();                     // every x read complete
#pragma unroll
        for (int tt = 0; tt < TPG; ++tt) {
            int row0 = (tt * 4 + q) * 64;
            *(float4*)&shx[(row0 + rg * 4 + 0) * 68 + cg * 4] = ac[tt][0];
            *(float4*)&shx[(row0 + rg * 4 + 1) * 68 + cg * 4] = ac[tt][1];
            *(float4*)&shx[(row0 + rg * 4 + 2) * 68 + cg * 4] = ac[tt][2];
            *(float4*)&shx[(row0 + rg * 4 + 3) * 68 + cg * 4] = ac[tt][3];
        }
    }
    // small inits, regions disjoint from hx write-back and sW
    if (t < 64) { sbw[t] = ((const float*)b4)[t]; hist[t] = 0; }
    for (int i = t; i < NPG; i += 1024) rnk[i] = 0;
    __syncthreads();                         // hx visible; hist zeroed

    // ================= phase D: r12-verbatim tail =================
    for (int i = t; i < NPG; i += 1024) {
        int c = min(rowcnt[nbase + i], 63);
        atomicAdd(&hist[c], 1);
    }
    __syncthreads();
    if (t < 64) {
        int v = hist[t], s = v;
#pragma unroll
        for (int off = 1; off < 64; off <<= 1) {
            int u = __shfl_up(s, off, 64);
            if (lane >= off) s += u;
        }
        hist[t] = s - v;
    }
    __syncthreads();
    for (int i = t; i < NPG; i += 1024) {
        int c = min(rowcnt[nbase + i], 63);
        int pos = atomicAdd(&hist[c], 1);
        perm[pos] = i;                       // sorted by degree -> lanes
    }
    __syncthreads();
    // conv, LPN lanes per node (r12 shape, depth-2 prefetch)
    {
        int idx2 = t >> LOG_LPN;
        int half = t & (LPN - 1);
        int nl = perm[idx2];
        int st = rowstart[nbase + nl], cn = rowcnt[nbase + nl];
        float di = dinv[nbase + nl], dii = di * di;
        int fb = half * QF;
        float4 acc[QF];
#pragma unroll
        for (int c = 0; c < QF; ++c) {
            float4 xv = *(const float4*)&shx[nl * 68 + (fb + c) * 4];
            acc[c].x = fmaf(xv.x, dii, sbw[(fb + c) * 4 + 0]);
            acc[c].y = fmaf(xv.y, dii, sbw[(fb + c) * 4 + 1]);
            acc[c].z = fmaf(xv.z, dii, sbw[(fb + c) * 4 + 2]);
            acc[c].w = fmaf(xv.w, dii, sbw[(fb + c) * 4 + 3]);
        }
        int2 p0 = (cn > 0) ? pairs[st] : make_int2(0, 0);
        int2 p1 = (cn > 1) ? pairs[st + 1] : make_int2(0, 0);
        for (int j = 0; j < cn; ++j) {
            int2 p2 = (j + 2 < cn) ? pairs[st + j + 2] : make_int2(0, 0);
            float cfv = __int_as_float(p0.y);
            int   s   = p0.x;
#pragma unroll
            for (int c = 0; c < QF; ++c)
                acc[c] = f4fma(cfv, *(const float4*)&shx[s * 68 + (fb + c) * 4], acc[c]);
            p0 = p1; p1 = p2;
        }
#pragma unroll
        for (int c = 0; c < QF; ++c) {
            acc[c].x = fmaxf(acc[c].x, 0.f); acc[c].y = fmaxf(acc[c].y, 0.f);
            acc[c].z = fmaxf(acc[c].z, 0.f); acc[c].w = fmaxf(acc[c].w, 0.f);
        }
        __syncthreads();                     // all conv reads of hx complete
#pragma unroll
        for (int c = 0; c < QF; ++c)
            *(float4*)&shx[nl * 68 + (fb + c) * 4] = acc[c];   // h over hx
    }
    __syncthreads();
    // hp = h . Wp
    if (t < 512) {
        int wv8 = t >> 6, sub4 = (t >> 4) & 3;
        float4 w4 = wp4[lane16];
#pragma unroll
        for (int p = 0; p < PASSES; ++p) {
            int n2 = p * 32 + wv8 * 4 + sub4;
            float4 a = *(const float4*)&shx[n2 * 68 + lane16 * 4];
            float tt = a.x * w4.x + a.y * w4.y + a.z * w4.z + a.w * w4.w;
            tt += __shfl_xor(tt, 1, 64); tt += __shfl_xor(tt, 2, 64);
            tt += __shfl_xor(tt, 4, 64); tt += __shfl_xor(tt, 8, 64);
            if (lane16 == 0) shp[n2] = tt;
        }
    }
    __syncthreads();
    // score conv
    if (t < NPG) {
        int i = perm[t];
        int st = rowstart[nbase + i], cn = rowcnt[nbase + i];
        float di = dinv[nbase + i];
        float a = fmaf(shp[i], di * di, bp[0]);
        int2 q0 = (cn > 0) ? pairs[st] : make_int2(0, 0);
        int2 q1 = (cn > 1) ? pairs[st + 1] : make_int2(0, 0);
        for (int j = 0; j < cn; ++j) {
            int2 q2 = (j + 2 < cn) ? pairs[st + j + 2] : make_int2(0, 0);
            a = fmaf(__int_as_float(q0.y), shp[q0.x], a);
            q0 = q1; q1 = q2;
        }
        ssc[i] = a;
    }
    __syncthreads();
    // exact top-k rank (split partials)
    {
        int part = t >> RLOG;
        int i = t & (NPG - 1);
        float si = ssc[i];
        int j0 = part * RCH;
        int rank = 0;
        for (int j = j0; j < j0 + RCH; j += 4) {
            float4 sj = *(const float4*)&ssc[j];
            rank += (sj.x > si) || (sj.x == si && j     < i);
            rank += (sj.y > si) || (sj.y == si && j + 1 < i);
            rank += (sj.z > si) || (sj.z == si && j + 2 < i);
            rank += (sj.w > si) || (sj.w == si && j + 3 < i);
        }
        atomicAdd(&rnk[i], rank);
    }
    __syncthreads();
    if (!FINAL)
        for (int i = t; i < NPG; i += 1024)
            nid_out[nbase + i] = (rnk[i] < K) ? (g * K + rnk[i]) : -1;
    // gated xn write + readout partials
    float4 mx = make_float4(-3.402823466e38f, -3.402823466e38f, -3.402823466e38f, -3.402823466e38f);
    float4 sm = make_float4(0.f, 0.f, 0.f, 0.f);
    if (t < 512) {
        int wv8 = t >> 6, sub4 = (t >> 4) & 3;
#pragma unroll
        for (int p = 0; p < PASSES; ++p) {
            int n2 = p * 32 + wv8 * 4 + sub4;
            int r = rnk[n2];
            if (r < K) {
                float gt = tanhf(ssc[n2]);
                float4 v = *(const float4*)&shx[n2 * 68 + lane16 * 4];
                v.x *= gt; v.y *= gt; v.z *= gt; v.w *= gt;
                if (!FINAL) xn4[((size_t)g * K + r) * 16 + lane16] = v;
                mx.x = fmaxf(mx.x, v.x); mx.y = fmaxf(mx.y, v.y);
                mx.z = fmaxf(mx.z, v.z); mx.w = fmaxf(mx.w, v.w);
                sm.x += v.x; sm.y += v.y; sm.z += v.z; sm.w += v.w;
            }
        }
    }
    int grp = t >> 4;
    __syncthreads();                         // perm/shp dead; smx/ssm overlay safe
    if (t < 512) {
        smx[grp * 16 + lane16] = mx;
        ssm[grp * 16 + lane16] = sm;
    }
    __syncthreads();
    if (grp == 0) {
#pragma unroll
        for (int u = 1; u < 32; ++u) {
            float4 a = smx[u * 16 + lane16], b = ssm[u * 16 + lane16];
            mx.x = fmaxf(mx.x, a.x); mx.y = fmaxf(mx.y, a.y);
            mx.z = fmaxf(mx.z, a.z); mx.w = fmaxf(mx.w, a.w);
            sm.x += b.x; sm.y += b.y; sm.z += b.z; sm.w += b.w;
        }
        float invK = 1.f / K;
        int c = lane16 * 4;
        float mr[4] = {mx.x, mx.y, mx.z, mx.w};
        float ar[4] = {sm.x * invK, sm.y * invK, sm.z * invK, sm.w * invK};
#pragma unroll
        for (int u = 0; u < 4; ++u) {
            if (FINAL) {
                out[g * 128 + c + u]      = 0.5f * (x1r[g * 128 + c + u]      + mr[u]);
                out[g * 128 + 64 + c + u] = 0.5f * (x1r[g * 128 + 64 + c + u] + ar[u]);
            } else {
                xr[g * 128 + c + u]      = mr[u];
                xr[g * 128 + 64 + c + u] = ar[u];
            }
        }
    }
}

extern "C" void kernel_launch(void* const* d_in, const int* in_sizes, int n_in,
                              void* d_out, int out_size, void* d_ws, size_t ws_size,
                              hipStream_t stream) {
    const float* x    = (const float*)d_in[0];
    const float* eatt = (const float*)d_in[1];
    const float* W1   = (const float*)d_in[2];
    const float* b1   = (const float*)d_in[3];
    const float* Wp1  = (const float*)d_in[4];
    const float* bp1  = (const float*)d_in[5];
    const float* W2   = (const float*)d_in[6];
    const float* b2   = (const float*)d_in[7];
    const float* Wp2  = (const float*)d_in[8];
    const float* bp2  = (const float*)d_in[9];
    const int*   esrc = (const int*)d_in[10];
    const int*   edst = (const int*)d_in[11];
    float* out = (float*)d_out;

    float* ws = (float*)d_ws;
    size_t o = 0;
    float* A    = ws + o; o += (size_t)N0 * 64;   // unused (kept layout)
    float* xn1  = ws + o; o += (size_t)N1_ * 64;
    int2*  prs  = (int2*)(ws + o); o += (size_t)NE * 2;
    int*   rst  = (int*)(ws + o); o += N0;
    int*   rcn  = (int*)(ws + o); o += N0;
    float* dinv = ws + o; o += N0;
    int*   nid  = (int*)(ws + o); o += N0;
    float* x1r  = ws + o; o += BG * 128;
    (void)A;

    // ---- stage 1: fused CSR + GEMM + conv/pool ----
    stage_kernel<NN, K1, false, false><<<BG, 1024, 0, stream>>>(
        esrc, edst, eatt, nullptr, nid, prs, rst, rcn, dinv,
        (const float4*)x, (const float4*)W1, (const float4*)b1,
        (const float4*)Wp1, bp1, (float4*)xn1, x1r, nullptr, nullptr);
    // ---- stage 2: fused CSR(remap) + GEMM + conv/pool + final readout ----
    stage_kernel<K1, K2, true, true><<<BG, 1024, 0, stream>>>(
        esrc, edst, eatt, nid, nullptr, prs, rst, rcn, dinv,
        (const float4*)xn1, (const float4*)W2, (const float4*)b2,
        (const float4*)Wp2, bp2, nullptr, nullptr, x1r, out);
}